// Round 1
// baseline (2407.870 us; speedup 1.0000x reference)
//
#include <hip/hip_runtime.h>
#include <stdint.h>

// Qwen3.5 MoE block: N=4096 tokens, H=2048, E=16, K=4, I_moe=1408, I_sh=5632
// Strategy: bf16 MFMA grouped GEMM. fp32 router (selection safety). Weights
// transposed+converted to bf16 in ws each call (fold into GEMM later rounds).

#define N_TOK 4096
#define H_DIM 2048
#define E_NUM 16
#define TOPK  4
#define IMOE  1408
#define ISH   5632
#define SLOTS (N_TOK*TOPK)       // 16384 (sum of per-expert counts, exact)

#define MT 128
#define NT 128
#define BK 32

typedef __attribute__((ext_vector_type(8))) short bf16x8;   // 8 bf16 = 4 VGPRs
typedef __attribute__((ext_vector_type(4))) float f32x4;

static __device__ inline unsigned short f2bf(float f) {
    union { float f; unsigned u; } v; v.f = f;
    unsigned r = v.u + 0x7fffu + ((v.u >> 16) & 1u);   // RNE
    return (unsigned short)(r >> 16);
}

// ---------------- fp32 -> bf16 (no transpose), for hidden_states ----------------
__global__ void cvt_h_kernel(const float* __restrict__ in, unsigned short* __restrict__ out, int n4) {
    int i = blockIdx.x * blockDim.x + threadIdx.x;
    if (i < n4) {
        float4 v = *(const float4*)(in + (size_t)i * 4);
        ushort4 o; o.x = f2bf(v.x); o.y = f2bf(v.y); o.z = f2bf(v.z); o.w = f2bf(v.w);
        *(ushort4*)(out + (size_t)i * 4) = o;
    }
}

// ---------------- fp32 [R,C] -> bf16 [C,R] (per z-slice) ----------------
__global__ void transpose_cvt_kernel(const float* __restrict__ in, unsigned short* __restrict__ out,
                                     int R, int C) {
    __shared__ float tile[32][33];
    const float* ip = in + (size_t)blockIdx.z * R * C;
    unsigned short* op = out + (size_t)blockIdx.z * R * C;
    int cb = blockIdx.x * 32, rb = blockIdx.y * 32;
    int tx = threadIdx.x, ty = threadIdx.y;            // (32, 8)
    for (int i = 0; i < 4; i++)
        tile[ty + i * 8][tx] = ip[(size_t)(rb + ty + i * 8) * C + cb + tx];
    __syncthreads();
    for (int i = 0; i < 4; i++)
        op[(size_t)(cb + ty + i * 8) * R + rb + tx] = f2bf(tile[tx][ty + i * 8]);
}

// ---------------- router: fp32 logits -> softmax -> top4 -> renorm; + sigmoid gate ----------------
__global__ __launch_bounds__(256) void router_kernel(
    const float* __restrict__ h, const float* __restrict__ rw, const float* __restrict__ gw,
    int* __restrict__ topk_idx, float* __restrict__ topk_w,
    float* __restrict__ sg, int* __restrict__ counts) {
    int n = blockIdx.x;
    const float* hp = h + (size_t)n * H_DIM;
    int t = threadIdx.x;
    int e = t >> 4, part = t & 15;
    const float* rp = rw + (size_t)e * H_DIM;
    float acc = 0.f;
    for (int j = part; j < H_DIM; j += 16) acc += hp[j] * rp[j];
    for (int d = 8; d; d >>= 1) acc += __shfl_down(acc, d, 16);
    __shared__ float logits[E_NUM];
    if (part == 0) logits[e] = acc;
    float sacc = 0.f;
    for (int j = t; j < H_DIM; j += 256) sacc += hp[j] * gw[j];
    __shared__ float sred[256];
    sred[t] = sacc;
    __syncthreads();
    for (int d = 128; d; d >>= 1) { if (t < d) sred[t] += sred[t + d]; __syncthreads(); }
    if (t == 0) {
        float m = logits[0];
        for (int i = 1; i < E_NUM; i++) m = fmaxf(m, logits[i]);
        float p[E_NUM]; float s = 0.f;
        for (int i = 0; i < E_NUM; i++) { p[i] = expf(logits[i] - m); s += p[i]; }
        float invs = 1.f / s;
        for (int i = 0; i < E_NUM; i++) p[i] *= invs;
        int idx[TOPK]; float val[TOPK]; float vs = 0.f;
        for (int k = 0; k < TOPK; k++) {
            int bi = 0; float bv = -1.f;
            for (int i = 0; i < E_NUM; i++) if (p[i] > bv) { bv = p[i]; bi = i; }
            idx[k] = bi; val[k] = bv; vs += bv; p[bi] = -2.f;
        }
        float inv = 1.f / fmaxf(vs, 1e-9f);
        for (int k = 0; k < TOPK; k++) {
            topk_idx[n * TOPK + k] = idx[k];
            topk_w[n * TOPK + k] = val[k] * inv;
            atomicAdd(&counts[idx[k]], 1);
        }
        sg[n] = 1.f / (1.f + expf(-sred[0]));
    }
}

// ---------------- exclusive scan of 16 counts (tiny) ----------------
__global__ void scan_kernel(const int* __restrict__ counts, int* __restrict__ offsets,
                            int* __restrict__ cursor) {
    int s = 0;
    for (int e = 0; e < E_NUM; e++) { offsets[e] = s; cursor[e] = s; s += counts[e]; }
}

// ---------------- scatter token->slot ----------------
__global__ void bucketize_kernel(const int* __restrict__ topk_idx, const float* __restrict__ topk_w,
                                 int* __restrict__ cursor, int* __restrict__ slot_tok,
                                 float* __restrict__ slot_w) {
    int n = blockIdx.x * blockDim.x + threadIdx.x;
    if (n >= N_TOK) return;
    for (int k = 0; k < TOPK; k++) {
        int e = topk_idx[n * TOPK + k];
        int s = atomicAdd(&cursor[e], 1);
        slot_tok[s] = n;
        slot_w[s] = topk_w[n * TOPK + k];
    }
}

// ---------------- gather bf16 token rows into slot order ----------------
__global__ __launch_bounds__(256) void gather_kernel(const unsigned short* __restrict__ hbf,
                                                     const int* __restrict__ slot_tok,
                                                     unsigned short* __restrict__ A) {
    int s = blockIdx.x;
    int tok = slot_tok[s];
    const uint4* src = (const uint4*)(hbf + (size_t)tok * H_DIM);
    uint4* dst = (uint4*)(A + (size_t)s * H_DIM);
    dst[threadIdx.x] = src[threadIdx.x];
}

// ---------------- fused gate/up GEMM + SiLU*mul -> bf16 act ----------------
// A [rows,K] bf16 row-major; BgT,BuT [e][N,K] bf16 (pre-transposed). act [rows,N] bf16.
__global__ __launch_bounds__(256) void gemm_dual_kernel(
    const unsigned short* __restrict__ A, const unsigned short* __restrict__ Bg,
    const unsigned short* __restrict__ Bu, unsigned short* __restrict__ act,
    const int* __restrict__ counts, const int* __restrict__ offsets,
    int K, int N, int fixedM) {
    int e = blockIdx.z;
    int c, off;
    if (counts) { c = counts[e]; off = offsets[e]; } else { c = fixedM; off = 0; }
    int mtile = blockIdx.y;
    if (mtile * MT >= c) return;
    int ntile = blockIdx.x;
    const unsigned short* Ab = A + (size_t)off * K;
    const unsigned short* Bgb = Bg + (size_t)e * N * K;
    const unsigned short* Bub = Bu + (size_t)e * N * K;
    unsigned short* actb = act + (size_t)off * N;

    __shared__ __align__(16) unsigned short As[MT * BK];
    __shared__ __align__(16) unsigned short Bgs[NT * BK];
    __shared__ __align__(16) unsigned short Bus[NT * BK];

    int t = threadIdx.x;
    int wave = t >> 6, lane = t & 63;
    int wm = wave >> 1, wn = wave & 1;
    int quad = lane >> 4, l16 = lane & 15;

    f32x4 accg[4][4], accu[4][4];
    for (int i = 0; i < 4; i++) for (int j = 0; j < 4; j++) { accg[i][j] = (f32x4)0.f; accu[i][j] = (f32x4)0.f; }

    int m0 = mtile * MT, n0 = ntile * NT;
    for (int kt = 0; kt < K; kt += BK) {
        __syncthreads();
        for (int i = 0; i < 2; i++) {
            int idx = t + i * 256;
            int row = idx >> 2, ch = idx & 3;
            *(uint4*)&As[row * BK + ch * 8]  = *(const uint4*)&Ab[(size_t)(m0 + row) * K + kt + ch * 8];
            *(uint4*)&Bgs[row * BK + ch * 8] = *(const uint4*)&Bgb[(size_t)(n0 + row) * K + kt + ch * 8];
            *(uint4*)&Bus[row * BK + ch * 8] = *(const uint4*)&Bub[(size_t)(n0 + row) * K + kt + ch * 8];
        }
        __syncthreads();
        bf16x8 af[4], bgf[4], buf[4];
        for (int mi = 0; mi < 4; mi++)
            af[mi] = *(const bf16x8*)&As[(wm * 64 + mi * 16 + l16) * BK + quad * 8];
        for (int ni = 0; ni < 4; ni++) {
            bgf[ni] = *(const bf16x8*)&Bgs[(wn * 64 + ni * 16 + l16) * BK + quad * 8];
            buf[ni] = *(const bf16x8*)&Bus[(wn * 64 + ni * 16 + l16) * BK + quad * 8];
        }
        for (int mi = 0; mi < 4; mi++)
            for (int ni = 0; ni < 4; ni++) {
                accg[mi][ni] = __builtin_amdgcn_mfma_f32_16x16x32_bf16(af[mi], bgf[ni], accg[mi][ni], 0, 0, 0);
                accu[mi][ni] = __builtin_amdgcn_mfma_f32_16x16x32_bf16(af[mi], buf[ni], accu[mi][ni], 0, 0, 0);
            }
    }
    for (int mi = 0; mi < 4; mi++) {
        for (int r = 0; r < 4; r++) {
            int rl = m0 + wm * 64 + mi * 16 + quad * 4 + r;
            if (rl < c) {
                size_t rowbase = (size_t)rl * N + n0 + wn * 64 + l16;
                for (int ni = 0; ni < 4; ni++) {
                    float g = accg[mi][ni][r];
                    float u = accu[mi][ni][r];
                    float a = (g / (1.f + __expf(-g))) * u;
                    actb[rowbase + ni * 16] = f2bf(a);
                }
            }
        }
    }
}

// ---------------- down GEMM + combine ----------------
// routed: atomicAdd(out[tok,:], w_slot * y). shared: out[row,:] += sg[row] * y.
__global__ __launch_bounds__(256) void gemm_down_kernel(
    const unsigned short* __restrict__ Aact, const unsigned short* __restrict__ Bd,
    float* __restrict__ out,
    const int* __restrict__ counts, const int* __restrict__ offsets,
    const int* __restrict__ slot_tok, const float* __restrict__ slot_w,
    const float* __restrict__ sg,
    int K, int N, int fixedM) {
    int e = blockIdx.z;
    bool routed = (counts != nullptr);
    int c, off;
    if (routed) { c = counts[e]; off = offsets[e]; } else { c = fixedM; off = 0; }
    int mtile = blockIdx.y;
    if (mtile * MT >= c) return;
    int ntile = blockIdx.x;
    const unsigned short* Ab = Aact + (size_t)off * K;
    const unsigned short* Bb = Bd + (size_t)e * N * K;

    __shared__ __align__(16) unsigned short As[MT * BK];
    __shared__ __align__(16) unsigned short Bs[NT * BK];

    int t = threadIdx.x;
    int wave = t >> 6, lane = t & 63;
    int wm = wave >> 1, wn = wave & 1;
    int quad = lane >> 4, l16 = lane & 15;

    f32x4 acc[4][4];
    for (int i = 0; i < 4; i++) for (int j = 0; j < 4; j++) acc[i][j] = (f32x4)0.f;

    int m0 = mtile * MT, n0 = ntile * NT;
    for (int kt = 0; kt < K; kt += BK) {
        __syncthreads();
        for (int i = 0; i < 2; i++) {
            int idx = t + i * 256;
            int row = idx >> 2, ch = idx & 3;
            *(uint4*)&As[row * BK + ch * 8] = *(const uint4*)&Ab[(size_t)(m0 + row) * K + kt + ch * 8];
            *(uint4*)&Bs[row * BK + ch * 8] = *(const uint4*)&Bb[(size_t)(n0 + row) * K + kt + ch * 8];
        }
        __syncthreads();
        bf16x8 af[4], bf[4];
        for (int mi = 0; mi < 4; mi++)
            af[mi] = *(const bf16x8*)&As[(wm * 64 + mi * 16 + l16) * BK + quad * 8];
        for (int ni = 0; ni < 4; ni++)
            bf[ni] = *(const bf16x8*)&Bs[(wn * 64 + ni * 16 + l16) * BK + quad * 8];
        for (int mi = 0; mi < 4; mi++)
            for (int ni = 0; ni < 4; ni++)
                acc[mi][ni] = __builtin_amdgcn_mfma_f32_16x16x32_bf16(af[mi], bf[ni], acc[mi][ni], 0, 0, 0);
    }
    for (int mi = 0; mi < 4; mi++) {
        for (int r = 0; r < 4; r++) {
            int rl = m0 + wm * 64 + mi * 16 + quad * 4 + r;
            if (rl < c) {
                int col = n0 + wn * 64 + l16;
                if (routed) {
                    int s = off + rl;
                    int tok = slot_tok[s];
                    float w = slot_w[s];
                    float* ob = out + (size_t)tok * N + col;
                    for (int ni = 0; ni < 4; ni++)
                        atomicAdd(ob + ni * 16, w * acc[mi][ni][r]);
                } else {
                    float w = sg[rl];
                    float* ob = out + (size_t)rl * N + col;
                    for (int ni = 0; ni < 4; ni++)
                        ob[ni * 16] += w * acc[mi][ni][r];
                }
            }
        }
    }
}

extern "C" void kernel_launch(void* const* d_in, const int* in_sizes, int n_in,
                              void* d_out, int out_size, void* d_ws, size_t ws_size,
                              hipStream_t stream) {
    const float* h   = (const float*)d_in[0];
    const float* rw  = (const float*)d_in[1];
    const float* wg  = (const float*)d_in[2];
    const float* wu  = (const float*)d_in[3];
    const float* wd  = (const float*)d_in[4];
    const float* shg = (const float*)d_in[5];
    const float* shu = (const float*)d_in[6];
    const float* shd = (const float*)d_in[7];
    const float* sgw = (const float*)d_in[8];
    float* out = (float*)d_out;

    char* ws = (char*)d_ws;
    size_t off = 0;
    auto alloc = [&](size_t b) { size_t o = off; off += (b + 255) & ~(size_t)255; return (void*)(ws + o); };

    int*   counts   = (int*)  alloc(E_NUM * 4);
    int*   offsets  = (int*)  alloc(E_NUM * 4);
    int*   cursor   = (int*)  alloc(E_NUM * 4);
    int*   topk_idx = (int*)  alloc((size_t)N_TOK * TOPK * 4);
    float* topk_w   = (float*)alloc((size_t)N_TOK * TOPK * 4);
    float* sg       = (float*)alloc((size_t)N_TOK * 4);
    int*   slot_tok = (int*)  alloc((size_t)SLOTS * 4);
    float* slot_w   = (float*)alloc((size_t)SLOTS * 4);
    unsigned short* h_bf  = (unsigned short*)alloc((size_t)N_TOK * H_DIM * 2);
    unsigned short* wgT   = (unsigned short*)alloc((size_t)E_NUM * IMOE * H_DIM * 2);
    unsigned short* wuT   = (unsigned short*)alloc((size_t)E_NUM * IMOE * H_DIM * 2);
    unsigned short* wdT   = (unsigned short*)alloc((size_t)E_NUM * H_DIM * IMOE * 2);
    unsigned short* shGT  = (unsigned short*)alloc((size_t)ISH * H_DIM * 2);
    unsigned short* shUT  = (unsigned short*)alloc((size_t)ISH * H_DIM * 2);
    unsigned short* shDT  = (unsigned short*)alloc((size_t)H_DIM * ISH * 2);
    unsigned short* Agath = (unsigned short*)alloc((size_t)(SLOTS + MT) * H_DIM * 2);
    unsigned short* actR  = (unsigned short*)alloc((size_t)(SLOTS + MT) * IMOE * 2);
    unsigned short* actS  = (unsigned short*)alloc((size_t)N_TOK * ISH * 2);
    (void)ws_size; (void)in_sizes; (void)n_in; (void)out_size;

    hipMemsetAsync(out, 0, (size_t)N_TOK * H_DIM * 4, stream);
    hipMemsetAsync(counts, 0, E_NUM * 4, stream);

    // bf16 conversions
    cvt_h_kernel<<<(N_TOK * H_DIM / 4 + 255) / 256, 256, 0, stream>>>(h, h_bf, N_TOK * H_DIM / 4);
    transpose_cvt_kernel<<<dim3(IMOE / 32, H_DIM / 32, E_NUM), dim3(32, 8), 0, stream>>>(wg, wgT, H_DIM, IMOE);
    transpose_cvt_kernel<<<dim3(IMOE / 32, H_DIM / 32, E_NUM), dim3(32, 8), 0, stream>>>(wu, wuT, H_DIM, IMOE);
    transpose_cvt_kernel<<<dim3(H_DIM / 32, IMOE / 32, E_NUM), dim3(32, 8), 0, stream>>>(wd, wdT, IMOE, H_DIM);
    transpose_cvt_kernel<<<dim3(ISH / 32, H_DIM / 32, 1), dim3(32, 8), 0, stream>>>(shg, shGT, H_DIM, ISH);
    transpose_cvt_kernel<<<dim3(ISH / 32, H_DIM / 32, 1), dim3(32, 8), 0, stream>>>(shu, shUT, H_DIM, ISH);
    transpose_cvt_kernel<<<dim3(H_DIM / 32, ISH / 32, 1), dim3(32, 8), 0, stream>>>(shd, shDT, ISH, H_DIM);

    // routing
    router_kernel<<<N_TOK, 256, 0, stream>>>(h, rw, sgw, topk_idx, topk_w, sg, counts);
    scan_kernel<<<1, 1, 0, stream>>>(counts, offsets, cursor);
    bucketize_kernel<<<N_TOK / 256, 256, 0, stream>>>(topk_idx, topk_w, cursor, slot_tok, slot_w);
    gather_kernel<<<SLOTS, 256, 0, stream>>>(h_bf, slot_tok, Agath);

    // routed experts: gate/up fused, then down + atomic combine
    gemm_dual_kernel<<<dim3(IMOE / NT, N_TOK / MT, E_NUM), 256, 0, stream>>>(
        Agath, wgT, wuT, actR, counts, offsets, H_DIM, IMOE, 0);
    // shared expert gate/up
    gemm_dual_kernel<<<dim3(ISH / NT, N_TOK / MT, 1), 256, 0, stream>>>(
        h_bf, shGT, shUT, actS, nullptr, nullptr, H_DIM, ISH, N_TOK);
    // routed down + scatter-combine
    gemm_down_kernel<<<dim3(H_DIM / NT, N_TOK / MT, E_NUM), 256, 0, stream>>>(
        actR, wdT, out, counts, offsets, slot_tok, slot_w, nullptr, IMOE, H_DIM, 0);
    // shared down + sigmoid-gated add
    gemm_down_kernel<<<dim3(H_DIM / NT, N_TOK / MT, 1), 256, 0, stream>>>(
        actS, shDT, out, nullptr, nullptr, nullptr, nullptr, sg, ISH, H_DIM, N_TOK);
}

// Round 2
// 1904.240 us; speedup vs baseline: 1.2645x; 1.2645x over previous
//
#include <hip/hip_runtime.h>
#include <stdint.h>

// Qwen3.5 MoE block: N=4096 tokens, H=2048, E=16, K=4, I_moe=1408, I_sh=5632
// R2: global_load_lds(16B) staging + XOR source-chunk swizzle (bank-conflict
// fix under glds's linear-LDS constraint) + dual tile 128x64 (64 AGPR acc,
// was 128 -> occupancy 1 wave/SIMD). Down stays 128x128 (64 AGPR) + glds.

#define N_TOK 4096
#define H_DIM 2048
#define E_NUM 16
#define TOPK  4
#define IMOE  1408
#define ISH   5632
#define SLOTS (N_TOK*TOPK)       // 16384

#define MT 128
#define BK 32                     // bf16 elems along k per tile (64 B, 4 chunks)

typedef __attribute__((ext_vector_type(8))) short bf16x8;   // 8 bf16 = 4 VGPRs
typedef __attribute__((ext_vector_type(4))) float f32x4;

static __device__ inline unsigned short f2bf(float f) {
    union { float f; unsigned u; } v; v.f = f;
    unsigned r = v.u + 0x7fffu + ((v.u >> 16) & 1u);   // RNE
    return (unsigned short)(r >> 16);
}

// async global->LDS, 16 bytes per lane. LDS dest = wave-uniform base + lane*16,
// so per-wave lds pointers must be consecutive 16B slots (they are: slot = tid).
static __device__ inline void glds16(const unsigned short* g, unsigned short* l) {
    __builtin_amdgcn_global_load_lds(
        (const __attribute__((address_space(1))) void*)g,
        (__attribute__((address_space(3))) void*)l, 16, 0, 0);
}

// ---------------- fp32 -> bf16 (no transpose), for hidden_states ----------------
__global__ void cvt_h_kernel(const float* __restrict__ in, unsigned short* __restrict__ out, int n4) {
    int i = blockIdx.x * blockDim.x + threadIdx.x;
    if (i < n4) {
        float4 v = *(const float4*)(in + (size_t)i * 4);
        ushort4 o; o.x = f2bf(v.x); o.y = f2bf(v.y); o.z = f2bf(v.z); o.w = f2bf(v.w);
        *(ushort4*)(out + (size_t)i * 4) = o;
    }
}

// ---------------- fp32 [R,C] -> bf16 [C,R] (per z-slice) ----------------
__global__ void transpose_cvt_kernel(const float* __restrict__ in, unsigned short* __restrict__ out,
                                     int R, int C) {
    __shared__ float tile[32][33];
    const float* ip = in + (size_t)blockIdx.z * R * C;
    unsigned short* op = out + (size_t)blockIdx.z * R * C;
    int cb = blockIdx.x * 32, rb = blockIdx.y * 32;
    int tx = threadIdx.x, ty = threadIdx.y;            // (32, 8)
    for (int i = 0; i < 4; i++)
        tile[ty + i * 8][tx] = ip[(size_t)(rb + ty + i * 8) * C + cb + tx];
    __syncthreads();
    for (int i = 0; i < 4; i++)
        op[(size_t)(cb + ty + i * 8) * R + rb + tx] = f2bf(tile[tx][ty + i * 8]);
}

// ---------------- router: fp32 logits -> softmax -> top4 -> renorm; + sigmoid gate ----------------
__global__ __launch_bounds__(256) void router_kernel(
    const float* __restrict__ h, const float* __restrict__ rw, const float* __restrict__ gw,
    int* __restrict__ topk_idx, float* __restrict__ topk_w,
    float* __restrict__ sg, int* __restrict__ counts) {
    int n = blockIdx.x;
    const float* hp = h + (size_t)n * H_DIM;
    int t = threadIdx.x;
    int e = t >> 4, part = t & 15;
    const float* rp = rw + (size_t)e * H_DIM;
    float acc = 0.f;
    for (int j = part; j < H_DIM; j += 16) acc += hp[j] * rp[j];
    for (int d = 8; d; d >>= 1) acc += __shfl_down(acc, d, 16);
    __shared__ float logits[E_NUM];
    if (part == 0) logits[e] = acc;
    float sacc = 0.f;
    for (int j = t; j < H_DIM; j += 256) sacc += hp[j] * gw[j];
    __shared__ float sred[256];
    sred[t] = sacc;
    __syncthreads();
    for (int d = 128; d; d >>= 1) { if (t < d) sred[t] += sred[t + d]; __syncthreads(); }
    if (t == 0) {
        float m = logits[0];
        for (int i = 1; i < E_NUM; i++) m = fmaxf(m, logits[i]);
        float p[E_NUM]; float s = 0.f;
        for (int i = 0; i < E_NUM; i++) { p[i] = expf(logits[i] - m); s += p[i]; }
        float invs = 1.f / s;
        for (int i = 0; i < E_NUM; i++) p[i] *= invs;
        int idx[TOPK]; float val[TOPK]; float vs = 0.f;
        for (int k = 0; k < TOPK; k++) {
            int bi = 0; float bv = -1.f;
            for (int i = 0; i < E_NUM; i++) if (p[i] > bv) { bv = p[i]; bi = i; }
            idx[k] = bi; val[k] = bv; vs += bv; p[bi] = -2.f;
        }
        float inv = 1.f / fmaxf(vs, 1e-9f);
        for (int k = 0; k < TOPK; k++) {
            topk_idx[n * TOPK + k] = idx[k];
            topk_w[n * TOPK + k] = val[k] * inv;
            atomicAdd(&counts[idx[k]], 1);
        }
        sg[n] = 1.f / (1.f + expf(-sred[0]));
    }
}

// ---------------- exclusive scan of 16 counts (tiny) ----------------
__global__ void scan_kernel(const int* __restrict__ counts, int* __restrict__ offsets,
                            int* __restrict__ cursor) {
    int s = 0;
    for (int e = 0; e < E_NUM; e++) { offsets[e] = s; cursor[e] = s; s += counts[e]; }
}

// ---------------- scatter token->slot ----------------
__global__ void bucketize_kernel(const int* __restrict__ topk_idx, const float* __restrict__ topk_w,
                                 int* __restrict__ cursor, int* __restrict__ slot_tok,
                                 float* __restrict__ slot_w) {
    int n = blockIdx.x * blockDim.x + threadIdx.x;
    if (n >= N_TOK) return;
    for (int k = 0; k < TOPK; k++) {
        int e = topk_idx[n * TOPK + k];
        int s = atomicAdd(&cursor[e], 1);
        slot_tok[s] = n;
        slot_w[s] = topk_w[n * TOPK + k];
    }
}

// ---------------- gather bf16 token rows into slot order ----------------
__global__ __launch_bounds__(256) void gather_kernel(const unsigned short* __restrict__ hbf,
                                                     const int* __restrict__ slot_tok,
                                                     unsigned short* __restrict__ A) {
    int s = blockIdx.x;
    int tok = slot_tok[s];
    const uint4* src = (const uint4*)(hbf + (size_t)tok * H_DIM);
    uint4* dst = (uint4*)(A + (size_t)s * H_DIM);
    dst[threadIdx.x] = src[threadIdx.x];
}

// ---------------- fused gate/up GEMM + SiLU*mul -> bf16 act ----------------
// Block tile: 128 rows x 64 cols, dual accumulators (gate & up share A-frags).
// Per wave (2x2 grid): 64x32, accg[4][2]+accu[4][2] = 64 AGPR.
// Staging: glds 16B, source-chunk XOR swizzle c^= (r>>1)&3 (2-way banks = free).
__global__ __launch_bounds__(256, 2) void gemm_dual_kernel(
    const unsigned short* __restrict__ A, const unsigned short* __restrict__ Bg,
    const unsigned short* __restrict__ Bu, unsigned short* __restrict__ act,
    const int* __restrict__ counts, const int* __restrict__ offsets,
    int K, int N, int fixedM) {
    int e = blockIdx.z;
    int c, off;
    if (counts) { c = counts[e]; off = offsets[e]; } else { c = fixedM; off = 0; }
    int mtile = blockIdx.y;
    if (mtile * MT >= c) return;
    int ntile = blockIdx.x;
    const unsigned short* Ab = A + (size_t)off * K;
    const unsigned short* Bgb = Bg + (size_t)e * N * K;
    const unsigned short* Bub = Bu + (size_t)e * N * K;
    unsigned short* actb = act + (size_t)off * N;

    __shared__ __align__(16) unsigned short As[MT * BK];      // 8 KB
    __shared__ __align__(16) unsigned short Bgs[64 * BK];     // 4 KB
    __shared__ __align__(16) unsigned short Bus[64 * BK];     // 4 KB

    int t = threadIdx.x;
    int wave = t >> 6, lane = t & 63;
    int wm = wave >> 1, wn = wave & 1;
    int quad = lane >> 4, l16 = lane & 15;

    f32x4 accg[4][2], accu[4][2];
    for (int i = 0; i < 4; i++) for (int j = 0; j < 2; j++) { accg[i][j] = (f32x4)0.f; accu[i][j] = (f32x4)0.f; }

    int m0 = mtile * MT, n0 = ntile * 64;
    // staging slot assignments (constant across k-steps)
    int rA0 = t >> 2, cA0 = (t & 3) ^ ((rA0 >> 1) & 3);
    int s1 = t + 256;
    int rA1 = s1 >> 2, cA1 = (s1 & 3) ^ ((rA1 >> 1) & 3);
    int rB = t >> 2, cB = (t & 3) ^ ((rB >> 1) & 3);

    for (int kt = 0; kt < K; kt += BK) {
        __syncthreads();
        glds16(&Ab[(size_t)(m0 + rA0) * K + kt + cA0 * 8], &As[t * 8]);
        glds16(&Ab[(size_t)(m0 + rA1) * K + kt + cA1 * 8], &As[s1 * 8]);
        glds16(&Bgb[(size_t)(n0 + rB) * K + kt + cB * 8], &Bgs[t * 8]);
        glds16(&Bub[(size_t)(n0 + rB) * K + kt + cB * 8], &Bus[t * 8]);
        __syncthreads();
        bf16x8 af[4], bgf[2], buf[2];
        for (int mi = 0; mi < 4; mi++) {
            int rowl = wm * 64 + mi * 16 + l16;
            af[mi] = *(const bf16x8*)&As[rowl * BK + ((quad ^ ((rowl >> 1) & 3)) * 8)];
        }
        for (int ni = 0; ni < 2; ni++) {
            int rowl = wn * 32 + ni * 16 + l16;
            int co = (quad ^ ((rowl >> 1) & 3)) * 8;
            bgf[ni] = *(const bf16x8*)&Bgs[rowl * BK + co];
            buf[ni] = *(const bf16x8*)&Bus[rowl * BK + co];
        }
        for (int mi = 0; mi < 4; mi++)
            for (int ni = 0; ni < 2; ni++) {
                accg[mi][ni] = __builtin_amdgcn_mfma_f32_16x16x32_bf16(af[mi], bgf[ni], accg[mi][ni], 0, 0, 0);
                accu[mi][ni] = __builtin_amdgcn_mfma_f32_16x16x32_bf16(af[mi], buf[ni], accu[mi][ni], 0, 0, 0);
            }
    }
    for (int mi = 0; mi < 4; mi++) {
        for (int r = 0; r < 4; r++) {
            int rl = m0 + wm * 64 + mi * 16 + quad * 4 + r;
            if (rl < c) {
                size_t rowbase = (size_t)rl * N + n0 + wn * 32 + l16;
                for (int ni = 0; ni < 2; ni++) {
                    float g = accg[mi][ni][r];
                    float u = accu[mi][ni][r];
                    float a = (g / (1.f + __expf(-g))) * u;
                    actb[rowbase + ni * 16] = f2bf(a);
                }
            }
        }
    }
}

// ---------------- down GEMM + combine ----------------
// 128x128 tile, per wave 64x64, acc[4][4] = 64 AGPR. glds + swizzle staging.
// routed: atomicAdd(out[tok,:], w_slot * y). shared: out[row,:] += sg[row] * y.
__global__ __launch_bounds__(256, 2) void gemm_down_kernel(
    const unsigned short* __restrict__ Aact, const unsigned short* __restrict__ Bd,
    float* __restrict__ out,
    const int* __restrict__ counts, const int* __restrict__ offsets,
    const int* __restrict__ slot_tok, const float* __restrict__ slot_w,
    const float* __restrict__ sg,
    int K, int N, int fixedM) {
    int e = blockIdx.z;
    bool routed = (counts != nullptr);
    int c, off;
    if (routed) { c = counts[e]; off = offsets[e]; } else { c = fixedM; off = 0; }
    int mtile = blockIdx.y;
    if (mtile * MT >= c) return;
    int ntile = blockIdx.x;
    const unsigned short* Ab = Aact + (size_t)off * K;
    const unsigned short* Bb = Bd + (size_t)e * N * K;

    __shared__ __align__(16) unsigned short As[MT * BK];      // 8 KB
    __shared__ __align__(16) unsigned short Bs[MT * BK];      // 8 KB

    int t = threadIdx.x;
    int wave = t >> 6, lane = t & 63;
    int wm = wave >> 1, wn = wave & 1;
    int quad = lane >> 4, l16 = lane & 15;

    f32x4 acc[4][4];
    for (int i = 0; i < 4; i++) for (int j = 0; j < 4; j++) acc[i][j] = (f32x4)0.f;

    int m0 = mtile * MT, n0 = ntile * MT;
    int rA0 = t >> 2, cA0 = (t & 3) ^ ((rA0 >> 1) & 3);
    int s1 = t + 256;
    int rA1 = s1 >> 2, cA1 = (s1 & 3) ^ ((rA1 >> 1) & 3);

    for (int kt = 0; kt < K; kt += BK) {
        __syncthreads();
        glds16(&Ab[(size_t)(m0 + rA0) * K + kt + cA0 * 8], &As[t * 8]);
        glds16(&Ab[(size_t)(m0 + rA1) * K + kt + cA1 * 8], &As[s1 * 8]);
        glds16(&Bb[(size_t)(n0 + rA0) * K + kt + cA0 * 8], &Bs[t * 8]);
        glds16(&Bb[(size_t)(n0 + rA1) * K + kt + cA1 * 8], &Bs[s1 * 8]);
        __syncthreads();
        bf16x8 af[4], bf[4];
        for (int mi = 0; mi < 4; mi++) {
            int rowl = wm * 64 + mi * 16 + l16;
            af[mi] = *(const bf16x8*)&As[rowl * BK + ((quad ^ ((rowl >> 1) & 3)) * 8)];
        }
        for (int ni = 0; ni < 4; ni++) {
            int rowl = wn * 64 + ni * 16 + l16;
            bf[ni] = *(const bf16x8*)&Bs[rowl * BK + ((quad ^ ((rowl >> 1) & 3)) * 8)];
        }
        for (int mi = 0; mi < 4; mi++)
            for (int ni = 0; ni < 4; ni++)
                acc[mi][ni] = __builtin_amdgcn_mfma_f32_16x16x32_bf16(af[mi], bf[ni], acc[mi][ni], 0, 0, 0);
    }
    for (int mi = 0; mi < 4; mi++) {
        for (int r = 0; r < 4; r++) {
            int rl = m0 + wm * 64 + mi * 16 + quad * 4 + r;
            if (rl < c) {
                int col = n0 + wn * 64 + l16;
                if (routed) {
                    int s = off + rl;
                    int tok = slot_tok[s];
                    float w = slot_w[s];
                    float* ob = out + (size_t)tok * N + col;
                    for (int ni = 0; ni < 4; ni++)
                        atomicAdd(ob + ni * 16, w * acc[mi][ni][r]);
                } else {
                    float w = sg[rl];
                    float* ob = out + (size_t)rl * N + col;
                    for (int ni = 0; ni < 4; ni++)
                        ob[ni * 16] += w * acc[mi][ni][r];
                }
            }
        }
    }
}

extern "C" void kernel_launch(void* const* d_in, const int* in_sizes, int n_in,
                              void* d_out, int out_size, void* d_ws, size_t ws_size,
                              hipStream_t stream) {
    const float* h   = (const float*)d_in[0];
    const float* rw  = (const float*)d_in[1];
    const float* wg  = (const float*)d_in[2];
    const float* wu  = (const float*)d_in[3];
    const float* wd  = (const float*)d_in[4];
    const float* shg = (const float*)d_in[5];
    const float* shu = (const float*)d_in[6];
    const float* shd = (const float*)d_in[7];
    const float* sgw = (const float*)d_in[8];
    float* out = (float*)d_out;

    char* ws = (char*)d_ws;
    size_t off = 0;
    auto alloc = [&](size_t b) { size_t o = off; off += (b + 255) & ~(size_t)255; return (void*)(ws + o); };

    int*   counts   = (int*)  alloc(E_NUM * 4);
    int*   offsets  = (int*)  alloc(E_NUM * 4);
    int*   cursor   = (int*)  alloc(E_NUM * 4);
    int*   topk_idx = (int*)  alloc((size_t)N_TOK * TOPK * 4);
    float* topk_w   = (float*)alloc((size_t)N_TOK * TOPK * 4);
    float* sg       = (float*)alloc((size_t)N_TOK * 4);
    int*   slot_tok = (int*)  alloc((size_t)SLOTS * 4);
    float* slot_w   = (float*)alloc((size_t)SLOTS * 4);
    unsigned short* h_bf  = (unsigned short*)alloc((size_t)N_TOK * H_DIM * 2);
    unsigned short* wgT   = (unsigned short*)alloc((size_t)E_NUM * IMOE * H_DIM * 2);
    unsigned short* wuT   = (unsigned short*)alloc((size_t)E_NUM * IMOE * H_DIM * 2);
    unsigned short* wdT   = (unsigned short*)alloc((size_t)E_NUM * H_DIM * IMOE * 2);
    unsigned short* shGT  = (unsigned short*)alloc((size_t)ISH * H_DIM * 2);
    unsigned short* shUT  = (unsigned short*)alloc((size_t)ISH * H_DIM * 2);
    unsigned short* shDT  = (unsigned short*)alloc((size_t)H_DIM * ISH * 2);
    unsigned short* Agath = (unsigned short*)alloc((size_t)(SLOTS + MT) * H_DIM * 2);
    unsigned short* actR  = (unsigned short*)alloc((size_t)(SLOTS + MT) * IMOE * 2);
    unsigned short* actS  = (unsigned short*)alloc((size_t)N_TOK * ISH * 2);
    (void)ws_size; (void)in_sizes; (void)n_in; (void)out_size;

    hipMemsetAsync(out, 0, (size_t)N_TOK * H_DIM * 4, stream);
    hipMemsetAsync(counts, 0, E_NUM * 4, stream);

    // bf16 conversions
    cvt_h_kernel<<<(N_TOK * H_DIM / 4 + 255) / 256, 256, 0, stream>>>(h, h_bf, N_TOK * H_DIM / 4);
    transpose_cvt_kernel<<<dim3(IMOE / 32, H_DIM / 32, E_NUM), dim3(32, 8), 0, stream>>>(wg, wgT, H_DIM, IMOE);
    transpose_cvt_kernel<<<dim3(IMOE / 32, H_DIM / 32, E_NUM), dim3(32, 8), 0, stream>>>(wu, wuT, H_DIM, IMOE);
    transpose_cvt_kernel<<<dim3(H_DIM / 32, IMOE / 32, E_NUM), dim3(32, 8), 0, stream>>>(wd, wdT, IMOE, H_DIM);
    transpose_cvt_kernel<<<dim3(ISH / 32, H_DIM / 32, 1), dim3(32, 8), 0, stream>>>(shg, shGT, H_DIM, ISH);
    transpose_cvt_kernel<<<dim3(ISH / 32, H_DIM / 32, 1), dim3(32, 8), 0, stream>>>(shu, shUT, H_DIM, ISH);
    transpose_cvt_kernel<<<dim3(H_DIM / 32, ISH / 32, 1), dim3(32, 8), 0, stream>>>(shd, shDT, ISH, H_DIM);

    // routing
    router_kernel<<<N_TOK, 256, 0, stream>>>(h, rw, sgw, topk_idx, topk_w, sg, counts);
    scan_kernel<<<1, 1, 0, stream>>>(counts, offsets, cursor);
    bucketize_kernel<<<N_TOK / 256, 256, 0, stream>>>(topk_idx, topk_w, cursor, slot_tok, slot_w);
    gather_kernel<<<SLOTS, 256, 0, stream>>>(h_bf, slot_tok, Agath);

    // routed experts: gate/up fused (N-tile 64), then down + atomic combine
    gemm_dual_kernel<<<dim3(IMOE / 64, N_TOK / MT, E_NUM), 256, 0, stream>>>(
        Agath, wgT, wuT, actR, counts, offsets, H_DIM, IMOE, 0);
    // shared expert gate/up
    gemm_dual_kernel<<<dim3(ISH / 64, N_TOK / MT, 1), 256, 0, stream>>>(
        h_bf, shGT, shUT, actS, nullptr, nullptr, H_DIM, ISH, N_TOK);
    // routed down + scatter-combine
    gemm_down_kernel<<<dim3(H_DIM / MT, N_TOK / MT, E_NUM), 256, 0, stream>>>(
        actR, wdT, out, counts, offsets, slot_tok, slot_w, nullptr, IMOE, H_DIM, 0);
    // shared down + sigmoid-gated add
    gemm_down_kernel<<<dim3(H_DIM / MT, N_TOK / MT, 1), 256, 0, stream>>>(
        actS, shDT, out, nullptr, nullptr, nullptr, nullptr, sg, ISH, H_DIM, N_TOK);
}